// Round 6
// baseline (332.349 us; speedup 1.0000x reference)
//
#include <hip/hip_runtime.h>
#include <hip/hip_bf16.h>
#include <cmath>

#define DM    768
#define DI    1536
#define NST   16
#define BATCH 2
#define SEQ   2048
#define TOK   (BATCH*SEQ)   // 4096
#define NC    64            // chunks per sequence
#define CL    32            // chunk length (NC*CL == SEQ)
#define KS    4             // split-K factor for BC projection
#define NBIG  (2*DI + DI)   // 4608 mega-GEMM output columns
#define KSO   4             // split-K factor for out-GEMM

#define BKK   64
#define NKT   (DM / BKK)    // 12 K-tiles for mega GEMM

typedef __hip_bfloat16 bf16;
typedef __attribute__((ext_vector_type(8))) short   short8;
typedef __attribute__((ext_vector_type(4))) short   shortx4;
typedef __attribute__((ext_vector_type(4))) float   floatx4;

typedef unsigned short ushort_t;
typedef unsigned int   uint_t;

__device__ __forceinline__ float b2f(ushort_t u)
{ return __uint_as_float(((uint_t)u) << 16); }
__device__ __forceinline__ ushort_t f2b(float f)
{ bf16 h = __float2bfloat16(f); return *(ushort_t*)&h; }

// ---------------------------------------------------------------------------
// async global->LDS, 16B per lane.
// ---------------------------------------------------------------------------
typedef __attribute__((address_space(1))) const void gvoid;
typedef __attribute__((address_space(3))) void lvoid;
__device__ __forceinline__ void gl_lds16(const void* g, void* lds_base)
{
  __builtin_amdgcn_global_load_lds((gvoid*)(uintptr_t)g,
                                   (lvoid*)(uint32_t)(uintptr_t)lds_base,
                                   16, 0, 0);
}

// fast softplus: max(v,0) + log(1+exp(-|v|))
__device__ __forceinline__ float softplus_f(float v)
{
  return fmaxf(v, 0.f) + __logf(1.f + __expf(-fabsf(v)));
}

// ---------------------------------------------------------------------------
// MEGA GEMM: [4096x768]@[768x4608], 256(M)x288(N) tile, BK=64 (ROUND 6 =
// ROUND 5 resubmitted after infra failure; kernel audited: barrier-uniform
// control flow, no OOB LDS/global access, vmcnt ledger consistent).
// R1-R4 post-mortem: t_block ~37us regardless of BK/pipeline; the 288-block
// grid's 2-round makespan (2 x t_block) was binding. Fix: grid 16x16 = 256
// blocks EXACTLY (zero tail) via 256x288 tiles at 8 WAVES (R3's spill was
// 12 waves -> 170-VGPR cap; 8 waves -> 2/SIMD -> 256 cap; demand ~240).
// Wave = 64(M) x 144(N) (4M x 2N), acc[4][9]; both A-halves kept live so
// no A re-reads. Phases per tile:
//   P1 (mh0,nh0): LDA(mh0)4 + LDB_N0 8           | 16 MFMA
//   P2 (mh1,nh0): LDA(mh1)4                       | 16 MFMA
//   P3 (mh1,nh1): LDB_N1 10 + STGA(T+2)           | 20 MFMA
//   P4 (mh0,nh1): STGB(T+2), vmcnt(9|8)           | 20 MFMA
// Liveness: A LDS last read P2 -> stage P3 (after P2's barrier, all waves'
// lgkm drained); B last read P3 -> stage P4. Counted drain at P4: per-tile
// per-wave issues = 4A + (5|4)B; vmcnt(9|8) drains T+1, keeps T+2.
// LDS 136 KiB (A 2x32K | B 2x36K), XOR-swizzle as before. Epilogue handles
// the xz/dt split per 16-col fragment (3072 % 16 == 0).
// ---------------------------------------------------------------------------
__global__ __launch_bounds__(512, 2)
void bgemm_mega8(const bf16* __restrict__ A,
                 const bf16* __restrict__ Bt,
                 const float* __restrict__ bias,
                 bf16* __restrict__ Cxz,
                 bf16* __restrict__ Cdt)
{
  // shorts: A buf b at b*16384 (32KB); B at 32768 + b*18432 (36KB)
  __shared__ __align__(16) short smem[69632];   // 136 KiB

  const int tid  = threadIdx.x;
  const int lane = tid & 63;
  const int wv   = tid >> 6;      // 0..7
  const int wm   = wv & 3;        // m quarter (64 rows)
  const int wn   = wv >> 2;       // n half (144 cols)

  // XCD-aware bijective swizzle (256 = 8*32), m fastest within XCD
  const int nb = (blockIdx.x & 7) * 32 + (blockIdx.x >> 3);
  const int m0 = (nb & 15) << 8;        // 16 m-tiles x 256
  const int n0 = (nb >> 4) * 288;       // 16 n-tiles x 288

  // staging: one gl_lds16 = 1KB = 8 rows x 128B; lane -> row lane>>3,
  // slot lane&7; source col pre-swizzled: slot ^= (row&7).
  const int srow8 = lane >> 3;
  const int scol  = ((lane & 7) ^ srow8) << 3;
  const int fr    = lane & 15;
  const int fq    = lane >> 4;
  const int xsw   = (fr & 7) << 3;      // ds_read short-offset XOR
  const int fq8x  = (fq * 8) ^ (xsw & 24);
  const int k0x   = xsw & 32;
  const uint32_t lbase = (uint32_t)(uintptr_t)smem;
  const uint32_t aB0 = lbase + (uint32_t)((wm*64 + fr) * 128 + 2*(k0x + fq8x));
  const uint32_t aB1 = lbase + (uint32_t)((wm*64 + fr) * 128 + 2*((32 ^ k0x) + fq8x));
  const uint32_t bB0 = lbase + 65536u + (uint32_t)((wn*144 + fr) * 128 + 2*(k0x + fq8x));
  const uint32_t bB1 = lbase + 65536u + (uint32_t)((wn*144 + fr) * 128 + 2*((32 ^ k0x) + fq8x));

  floatx4 acc[4][9];
  #pragma unroll
  for (int i = 0; i < 4; ++i)
    #pragma unroll
    for (int j = 0; j < 9; ++j)
      acc[i][j] = (floatx4){0.f, 0.f, 0.f, 0.f};

  short8 Af[8], Bf[10];

  // A staging: all 8 waves, rows [wv*32, wv*32+32), 4 issues
  #define STGA(buf, kt) { _Pragma("unroll") for (int q = 0; q < 4; ++q)       \
      gl_lds16(A + (size_t)(m0 + wv*32 + q*8 + srow8) * DM + (kt) + scol,     \
               smem + (buf)*16384 + (wv*32 + q*8)*64); }
  // B staging: waves 0-3 rows [wv*40,+40) (5 issues); 4-7 [160+(wv-4)*32,+32)
  #define STGB(buf, kt) { if (wv < 4) {                                       \
      _Pragma("unroll") for (int q = 0; q < 5; ++q)                           \
        gl_lds16(Bt + (size_t)(n0 + wv*40 + q*8 + srow8) * DM + (kt) + scol,  \
                 smem + 32768 + (buf)*18432 + (wv*40 + q*8)*64);              \
    } else {                                                                  \
      _Pragma("unroll") for (int q = 0; q < 4; ++q)                           \
        gl_lds16(Bt + (size_t)(n0 + 160 + (wv-4)*32 + q*8 + srow8) * DM       \
                    + (kt) + scol,                                            \
                 smem + 32768 + (buf)*18432 + (160 + (wv-4)*32 + q*8)*64);    \
    } }

  #define DSR(dst, a) asm volatile("ds_read_b128 %0, %1" : "=v"(dst) : "v"(a))
  // A m-half mh into Af[mh*4..]: 2 mfrags (stride 16 rows = 2048B) x 2 kk
  #define LDA(bo, mh) {                                                       \
    DSR(Af[(mh)*4+0], aB0 + (bo) + (mh)*4096);                                \
    DSR(Af[(mh)*4+1], aB1 + (bo) + (mh)*4096);                                \
    DSR(Af[(mh)*4+2], aB0 + (bo) + (mh)*4096 + 2048);                         \
    DSR(Af[(mh)*4+3], aB1 + (bo) + (mh)*4096 + 2048); }
  // B nh0: nf 0..3 -> Bf[0..7]
  #define LDB_N0(bo) {                                                        \
    DSR(Bf[0], bB0+(bo));        DSR(Bf[1], bB1+(bo));                        \
    DSR(Bf[2], bB0+(bo)+2048);   DSR(Bf[3], bB1+(bo)+2048);                   \
    DSR(Bf[4], bB0+(bo)+4096);   DSR(Bf[5], bB1+(bo)+4096);                   \
    DSR(Bf[6], bB0+(bo)+6144);   DSR(Bf[7], bB1+(bo)+6144); }
  // B nh1: nf 4..8 -> Bf[0..9]
  #define LDB_N1(bo) {                                                        \
    DSR(Bf[0], bB0+(bo)+8192);   DSR(Bf[1], bB1+(bo)+8192);                   \
    DSR(Bf[2], bB0+(bo)+10240);  DSR(Bf[3], bB1+(bo)+10240);                  \
    DSR(Bf[4], bB0+(bo)+12288);  DSR(Bf[5], bB1+(bo)+12288);                  \
    DSR(Bf[6], bB0+(bo)+14336);  DSR(Bf[7], bB1+(bo)+14336);                  \
    DSR(Bf[8], bB0+(bo)+16384);  DSR(Bf[9], bB1+(bo)+16384); }

  // MFMA cluster; acc col base 0 (nh0, cnt 4) or 4 (nh1, cnt 5)
  #define MMA(mh, base, cnt)                                                  \
    { __builtin_amdgcn_sched_barrier(0);                                      \
      __builtin_amdgcn_s_setprio(1);                                          \
      _Pragma("unroll") for (int m2 = 0; m2 < 2; ++m2)                        \
      _Pragma("unroll") for (int nf = 0; nf < (cnt); ++nf)                    \
      _Pragma("unroll") for (int kk = 0; kk < 2; ++kk)                        \
        acc[(mh)*2+m2][(base)+nf] = __builtin_amdgcn_mfma_f32_16x16x32_bf16(  \
            Af[(mh)*4+m2*2+kk], Bf[nf*2+kk], acc[(mh)*2+m2][(base)+nf],0,0,0);\
      __builtin_amdgcn_s_setprio(0);                                          \
      __builtin_amdgcn_sched_barrier(0); }

  #define BAR()   __builtin_amdgcn_s_barrier()
  #define LGKM0() asm volatile("s_waitcnt lgkmcnt(0)" ::: "memory")
  #define VMT()   { if (wv < 4) asm volatile("s_waitcnt vmcnt(9)" ::: "memory"); \
                    else        asm volatile("s_waitcnt vmcnt(8)" ::: "memory"); }
  #define VM0()   asm volatile("s_waitcnt vmcnt(0)" ::: "memory")

  // prologue: stage T0 + T1; drain T0 (oldest 9|8), keep T1 in flight
  STGA(0, 0); STGB(0, 0);
  STGA(1, BKK); STGB(1, BKK);
  VMT(); BAR();

  // one tile: buf b, next-next K offset ktn, guard g
  #define TILE(b, ktn, g)                                                     \
    LDA((b)*32768, 0); LDB_N0((b)*36864);                                     \
    BAR(); LGKM0(); MMA(0, 0, 4); BAR();                                      \
    LDA((b)*32768, 1);                                                        \
    BAR(); LGKM0(); MMA(1, 0, 4); BAR();                                      \
    LDB_N1((b)*36864);                                                        \
    if (g) STGA(b, ktn);                                                      \
    BAR(); LGKM0(); MMA(1, 4, 5); BAR();                                      \
    if (g) STGB(b, ktn);                                                      \
    BAR(); MMA(0, 4, 5);                                                      \
    if (g) { VMT(); } else { VM0(); }                                         \
    BAR();

  #pragma unroll 1
  for (int i = 0; i < NKT/2; ++i) {
    const int kt2 = (2*i + 2) * BKK;
    const int kt3 = (2*i + 3) * BKK;
    const bool g  = (2*i + 3) < NKT;    // covers both T+2 stages
    TILE(0, kt2, g)
    TILE(1, kt3, g)
  }

  #undef STGA
  #undef STGB
  #undef DSR
  #undef LDA
  #undef LDB_N0
  #undef LDB_N1
  #undef MMA
  #undef TILE

  // epilogue: all loop reads drained; repurpose LDS for per-wave transpose
  VM0(); BAR();

  short* st = smem + wv * 2368;          // 16 x 148 shorts per wave
  bool  fdt[9];
  float bv[9];
  #pragma unroll
  for (int nf = 0; nf < 9; ++nf) {
    const int gc = n0 + wn * 144 + nf * 16;
    fdt[nf] = (gc >= 2 * DI);
    bv[nf]  = fdt[nf] ? bias[gc - 2 * DI + fr] : 0.f;
  }

  #pragma unroll
  for (int mf = 0; mf < 4; ++mf) {
    #pragma unroll
    for (int nf = 0; nf < 9; ++nf)
      #pragma unroll
      for (int r = 0; r < 4; ++r) {
        float v = acc[mf][nf][r];
        if (fdt[nf]) v = softplus_f(v + bv[nf]);
        st[(fq * 4 + r) * 148 + nf * 16 + fr] = (short)f2b(v);
      }
    // readout: 16 rows x 144 cols in 8B grains: 576 = 9 passes x 64 lanes
    #pragma unroll
    for (int p = 0; p < 9; ++p) {
      const int idx = p * 64 + lane;
      const int row = idx / 36;
      const int off = idx - row * 36;
      shortx4 val = *(const shortx4*)&st[row * 148 + off * 4];
      const int gcol = n0 + wn * 144 + off * 4;
      const int grow = m0 + wm * 64 + mf * 16 + row;
      if (gcol >= 2 * DI)
        *(shortx4*)(Cdt + (size_t)grow * DI + (gcol - 2 * DI)) = val;
      else
        *(shortx4*)(Cxz + (size_t)grow * (2 * DI) + gcol) = val;
    }
  }

  #undef BAR
  #undef LGKM0
  #undef VMT
  #undef VM0
}

// ---------------------------------------------------------------------------
// OUT GEMM: 128x128 tile, split-K x KSO, PARTIAL STORES (deterministic).
// [4096x1536]@[1536x768] -> grid (6, 32, 4) = 768 blocks, 12 iters each.
// Partial z stored at Op + z*TOK*DM.
// ---------------------------------------------------------------------------
__global__ __launch_bounds__(256)
void bgemm_sk(const bf16* __restrict__ A, int lda,
              const bf16* __restrict__ Bt, int ldb,
              float* __restrict__ Op, int ldc,
              int kLen)
{
  __shared__ short sA[2][128 * 32];
  __shared__ short sB[2][128 * 32];

  const int tid  = threadIdx.x;
  const int lane = tid & 63;
  const int wv   = tid >> 6;
  const int wm   = wv >> 1;
  const int wn   = wv & 1;
  const int m0   = blockIdx.y * 128;
  const int n0   = blockIdx.x * 128;
  const int kS   = blockIdx.z * kLen;

  const int srow = lane >> 2;
  const int skof = (lane & 3) * 8;
  const int fr   = lane & 15;
  const int fq   = lane >> 4;

  floatx4 acc[4][4];
  #pragma unroll
  for (int i = 0; i < 4; ++i)
    #pragma unroll
    for (int j = 0; j < 4; ++j)
      acc[i][j] = (floatx4){0.f, 0.f, 0.f, 0.f};

  #define STAGE_SK(p, k0)                                                     \
    { _Pragma("unroll")                                                       \
      for (int q = 0; q < 2; ++q) {                                           \
        const int r = (wv * 2 + q) * 16 + srow;                               \
        gl_lds16(A  + (size_t)(m0 + r) * lda + kS + (k0) + skof,              \
                 &sA[p][(wv * 2 + q) * 512]);                                 \
        gl_lds16(Bt + (size_t)(n0 + r) * ldb + kS + (k0) + skof,              \
                 &sB[p][(wv * 2 + q) * 512]);                                 \
      } }

  STAGE_SK(0, 0);
  int p = 0;
  for (int k0 = 0; k0 < kLen; k0 += 32, p ^= 1) {
    __syncthreads();
    if (k0 + 32 < kLen) STAGE_SK(p ^ 1, k0 + 32);

    short8 af[4], bfv[4];
    #pragma unroll
    for (int t = 0; t < 4; ++t) {
      af[t]  = *(const short8*)&sA[p][(wm * 64 + t * 16 + fr) * 32 + fq * 8];
      bfv[t] = *(const short8*)&sB[p][(wn * 64 + t * 16 + fr) * 32 + fq * 8];
    }
    #pragma unroll
    for (int i = 0; i < 4; ++i)
      #pragma unroll
      for (int j = 0; j < 4; ++j)
        acc[i][j] = __builtin_amdgcn_mfma_f32_16x16x32_bf16(af[i], bfv[j], acc[i][j], 0, 0, 0);
  }
  #undef STAGE_SK

  float* Co = Op + (size_t)blockIdx.z * ((size_t)TOK * DM);
  const int crow0 = m0 + wm * 64 + fq * 4;
  const int ccol0 = n0 + wn * 64 + fr;
  #pragma unroll
  for (int j = 0; j < 4; ++j) {
    const int col = ccol0 + j * 16;
    #pragma unroll
    for (int i = 0; i < 4; ++i)
      #pragma unroll
      for (int r = 0; r < 4; ++r)
        Co[(size_t)(crow0 + i * 16 + r) * ldc + col] = acc[i][j][r];
  }
}

// sum KSO fp32 partials -> fp32 out
__global__ __launch_bounds__(256)
void out_reduce(const float* __restrict__ Op, float* __restrict__ out)
{
  const int i = (blockIdx.x * 256 + threadIdx.x) * 4;   // < TOK*DM
  float4 s = *(const float4*)(Op + i);
  #pragma unroll
  for (int z = 1; z < KSO; ++z) {
    float4 v = *(const float4*)(Op + (size_t)z * TOK * DM + i);
    s.x += v.x; s.y += v.y; s.z += v.z; s.w += v.w;
  }
  *(float4*)(out + i) = s;
}

// ---------------------------------------------------------------------------
// bf16 MFMA GEMM, 64(M)x128(N) tile, BK=32, double-buffered, split-K part
// store (Wcomb precompute).
// ---------------------------------------------------------------------------
__global__ __launch_bounds__(256)
void bgemm64p(const bf16* __restrict__ A, int lda,
              const bf16* __restrict__ Bt, int ldb,
              float* __restrict__ C, int ldc,
              size_t partStride, int kLen)
{
  __shared__ short sA[2][64 * 32];
  __shared__ short sB[2][128 * 32];

  const int tid  = threadIdx.x;
  const int lane = tid & 63;
  const int wv   = tid >> 6;
  const int m0   = blockIdx.y * 64;
  const int n0   = blockIdx.x * 128;
  const int kS   = blockIdx.z * kLen;

  const int srow = lane >> 2;
  const int skof = (lane & 3) * 8;
  const int fr   = lane & 15;
  const int fq   = lane >> 4;

  floatx4 acc[4][2];
  #pragma unroll
  for (int i = 0; i < 4; ++i)
    #pragma unroll
    for (int j = 0; j < 2; ++j)
      acc[i][j] = (floatx4){0.f, 0.f, 0.f, 0.f};

  #define STAGE64(p, k0)                                                      \
    { const int ra = wv * 16 + srow;                                          \
      gl_lds16(A + (size_t)(m0 + ra) * lda + kS + (k0) + skof,                \
               &sA[p][wv * 512]);                                             \
      _Pragma("unroll")                                                       \
      for (int q = 0; q < 2; ++q) {                                           \
        const int rb = (wv * 2 + q) * 16 + srow;                              \
        gl_lds16(Bt + (size_t)(n0 + rb) * ldb + kS + (k0) + skof,             \
                 &sB[p][(wv * 2 + q) * 512]);                                 \
      } }

  STAGE64(0, 0);
  int p = 0;
  for (int k0 = 0; k0 < kLen; k0 += 32, p ^= 1) {
    __syncthreads();
    if (k0 + 32 < kLen) STAGE64(p ^ 1, k0 + 32);

    short8 af[4], bfv[2];
    #pragma unroll
    for (int t = 0; t < 4; ++t)
      af[t] = *(const short8*)&sA[p][(t * 16 + fr) * 32 + fq * 8];
    #pragma unroll
    for (int j = 0; j < 2; ++j)
      bfv[j] = *(const short8*)&sB[p][(wv * 32 + j * 16 + fr) * 32 + fq * 8];
    #pragma unroll
    for (int i = 0; i < 4; ++i)
      #pragma unroll
      for (int j = 0; j < 2; ++j)
        acc[i][j] = __builtin_amdgcn_mfma_f32_16x16x32_bf16(af[i], bfv[j], acc[i][j], 0, 0, 0);
  }
  #undef STAGE64

  float* Co = C + (size_t)blockIdx.z * partStride;
  const int crow0 = m0 + fq * 4;
  const int ccol0 = n0 + wv * 32 + fr;
  #pragma unroll
  for (int j = 0; j < 2; ++j) {
    const int col = ccol0 + j * 16;
    #pragma unroll
    for (int i = 0; i < 4; ++i)
      #pragma unroll
      for (int r = 0; r < 4; ++r)
        Co[(size_t)(crow0 + i * 16 + r) * ldc + col] = acc[i][j][r];
  }
}

// ---------------------------------------------------------------------------
// merged prep: 3 weight transposes + cast x + cast W_in (one launch).
// blocks [0,2304): W_in tiles; [2304,4608): W_dt; [4608,5760): W_out;
// [5760, ...): elementwise casts (1024 elems/block).
// ---------------------------------------------------------------------------
__device__ __forceinline__ void tcast_tile(const float* W, bf16* Wt,
                                           int K, int N, int tx, int ty,
                                           int tid)
{
  __shared__ float t[32][33];
  const int n0 = tx * 32, k0 = ty * 32;
  const int x = tid & 31, y = tid >> 5;
  #pragma unroll
  for (int i = 0; i < 32; i += 8)
    t[y + i][x] = W[(size_t)(k0 + y + i) * N + n0 + x];
  __syncthreads();
  #pragma unroll
  for (int i = 0; i < 32; i += 8)
    Wt[(size_t)(n0 + y + i) * K + k0 + x] = __float2bfloat16(t[x][y + i]);
}

__global__ __launch_bounds__(256)
void prep_all(const float* __restrict__ x,    const float* __restrict__ W_in,
              const float* __restrict__ W_dt, const float* __restrict__ W_out,
              bf16* __restrict__ x_bf,   bf16* __restrict__ Win_bf,
              bf16* __restrict__ Bt_big, bf16* __restrict__ Wt_dt,
              bf16* __restrict__ Wt_out)
{
  const int bid = blockIdx.x;
  const int tid = threadIdx.x;
  if (bid < 2304) {
    tcast_tile(W_in,  Bt_big, DM, 2 * DI, bid % 96, bid / 96, tid);
  } else if (bid < 4608) {
    int b = bid - 2304;
    tcast_tile(W_dt,  Wt_dt,  DI, DI,     b % 48,  b / 48,  tid);
  } else if (bid < 5760) {
    int b = bid - 4608;
    tcast_tile(W_out, Wt_out, DI, DM,     b % 24,  b / 24,  tid);
  } else {
    const int n1 = TOK * DM;                  // x elements
    int i = (bid - 5760) * 1024 + tid * 4;
    const float* s; bf16* d;
    if (i < n1) { s = x; d = x_bf; }
    else        { s = W_in; d = Win_bf; i -= n1; }
    float4 v = *(const float4*)(s + i);
    d[i + 0] = __float2bfloat16(v.x); d[i + 1] = __float2bfloat16(v.y);
    d[i + 2] = __float2bfloat16(v.z); d[i + 3] = __float2bfloat16(v.w);
  }
}

// sum 4 fp32 partials -> bf16 (Wcomb reduce into Bt_big rows [3072,4608))
__global__ __launch_bounds__(256)
void wcomb_reduce(const float* __restrict__ P, bf16* __restrict__ dst)
{
  const int i = (blockIdx.x * 256 + threadIdx.x) * 4;   // < DI*DM
  float4 s = *(const float4*)(P + i);
  #pragma unroll
  for (int ks = 1; ks < 4; ++ks) {
    float4 v = *(const float4*)(P + (size_t)ks * DI * DM + i);
    s.x += v.x; s.y += v.y; s.z += v.z; s.w += v.w;
  }
  dst[i + 0] = __float2bfloat16(s.x);
  dst[i + 1] = __float2bfloat16(s.y);
  dst[i + 2] = __float2bfloat16(s.z);
  dst[i + 3] = __float2bfloat16(s.w);
}

// ---------------------------------------------------------------------------
// BC projection, split-K fp32 accumulate over bf16 x_p.
// ---------------------------------------------------------------------------
__global__ __launch_bounds__(256)
void bc_partial(const ushort_t* __restrict__ xzb, const float* __restrict__ Wx,
                float* __restrict__ BCp)
{
  const int tok = blockIdx.x * 8 + (threadIdx.x >> 5);
  const int j   = threadIdx.x & 31;
  const int k0  = blockIdx.y * (DI / KS);
  const ushort_t* xrow = xzb + (size_t)tok * (2 * DI) + k0;
  const float* wp = Wx + (size_t)k0 * 32 + j;
  float a0 = 0.f, a1 = 0.f, a2 = 0.f, a3 = 0.f;
  #pragma unroll 8
  for (int k = 0; k < DI / KS; k += 4) {
    ushort4 xv = *(const ushort4*)(xrow + k);
    a0 = fmaf(b2f(xv.x), wp[(k + 0) * 32], a0);
    a1 = fmaf(b2f(xv.y), wp[(k + 1) * 32], a1);
    a2 = fmaf(b2f(xv.z), wp[(k + 2) * 32], a2);
    a3 = fmaf(b2f(xv.w), wp[(k + 3) * 32], a3);
  }
  BCp[((size_t)blockIdx.y * TOK + tok) * 32 + j] = (a0 + a1) + (a2 + a3);
}

// stage BC for a chunk: sum the KS split-K partials during LDS fill
__device__ __forceinline__ void stage_bc(const float* __restrict__ BCp,
                                         int g0, int tid, float bcs[CL][32])
{
  int t = tid >> 3, q = (tid & 7) << 2;
  float4 s = *(const float4*)(BCp + ((size_t)(g0 + t)) * 32 + q);
  #pragma unroll
  for (int ks = 1; ks < KS; ++ks) {
    float4 v = *(const float4*)(BCp + ((size_t)ks * TOK + g0 + t) * 32 + q);
    s.x += v.x; s.y += v.y; s.z += v.z; s.w += v.w;
  }
  *(float4*)&bcs[t][q] = s;
}

// ---------------------------------------------------------------------------
// Scan (3 kernels). A_n = -(n+1); dA_n = e1^(n+1), e1 = exp(-dt).
// bf16 dt / S / Carry.
// ---------------------------------------------------------------------------
__global__ __launch_bounds__(256)
void scan_phase1(const ushort_t* __restrict__ xzb, const ushort_t* __restrict__ dtb,
                 const float* __restrict__ BCp,
                 ushort_t* __restrict__ S, float* __restrict__ sdt)
{
  const int d  = blockIdx.x * 256 + threadIdx.x;
  const int c  = blockIdx.y;
  const int b  = blockIdx.z;
  const int g0 = b * SEQ + c * CL;
  const int tid = threadIdx.x;

  __shared__ float bcs[CL][32];
  stage_bc(BCp, g0, tid, bcs);
  __syncthreads();

  float h[NST];
  #pragma unroll
  for (int n = 0; n < NST; ++n) h[n] = 0.f;
  float sd = 0.f;

  for (int t = 0; t < CL; ++t) {
    float dtv = b2f(dtb[(size_t)(g0 + t) * DI + d]);
    float xpv = b2f(xzb[(size_t)(g0 + t) * (2 * DI) + d]);
    sd += dtv;
    float xb = xpv * dtv;
    float e1 = __expf(-dtv);
    float dA = 1.f;
    #pragma unroll
    for (int n = 0; n < NST; ++n) {
      dA *= e1;
      h[n] = fmaf(dA, h[n], xb * bcs[t][n]);
    }
  }
  const size_t base = ((size_t)(b * NC + c) * NST) * DI + d;
  #pragma unroll
  for (int n = 0; n < NST; ++n) S[base + (size_t)n * DI] = f2b(h[n]);
  sdt[(size_t)(b * NC + c) * DI + d] = sd;
}

__global__ __launch_bounds__(256)
void scan_phase2(const ushort_t* __restrict__ S, const float* __restrict__ sdt,
                 ushort_t* __restrict__ Carry)
{
  const int f = blockIdx.x * 256 + threadIdx.x;   // < BATCH*NST*DI
  const int b = f / (NST * DI);
  const int r = f - b * (NST * DI);
  const int n = r / DI;
  const int d = r - n * DI;
  const float an = -(float)(n + 1);
  float carry = 0.f;
  #pragma unroll 8
  for (int c = 0; c < NC; ++c) {
    size_t idx = ((size_t)(b * NC + c) * NST + n) * DI + d;
    Carry[idx] = f2b(carry);
    float P = __expf(an * sdt[(size_t)(b * NC + c) * DI + d]);
    carry = fmaf(P, carry, b2f(S[idx]));
  }
}

__global__ __launch_bounds__(256)
void scan_phase3(const ushort_t* __restrict__ xzb, const ushort_t* __restrict__ dtb,
                 const float* __restrict__ BCp, const float* __restrict__ Dv,
                 const ushort_t* __restrict__ Carry, bf16* __restrict__ ygb)
{
  const int d  = blockIdx.x * 256 + threadIdx.x;
  const int c  = blockIdx.y;
  const int b  = blockIdx.z;
  const int g0 = b * SEQ + c * CL;
  const int tid = threadIdx.x;

  __shared__ float bcs[CL][32];
  stage_bc(BCp, g0, tid, bcs);
  __syncthreads();

  const size_t base = ((size_t)(b * NC + c) * NST) * DI + d;
  float h[NST];
  #pragma unroll
  for (int n = 0; n < NST; ++n) h[n] = b2f(Carry[base + (size_t)n * DI]);
  const float Dd = Dv[d];

  for (int t = 0; t < CL; ++t) {
    float dtv = b2f(dtb[(size_t)(g0 + t) * DI + d]);
    float xpv = b2f(xzb[(size_t)(g0 + t) * (2 * DI) + d]);
    float zv  = b2f(xzb[(size_t)(g0 + t) * (2 * DI) + DI + d]);
    float xb = xpv * dtv;
    float e1 = __expf(-dtv);
    float dA = 1.f;
    float y = 0.f;
    #pragma unroll
    for (int n = 0; n < NST; ++n) {
      dA *= e1;
      h[n] = fmaf(dA, h[n], xb * bcs[t][n]);
      y = fmaf(h[n], bcs[t][16 + n], y);
    }
    y = fmaf(xpv, Dd, y);
    float sil = zv / (1.f + __expf(-zv));
    ygb[(size_t)(g0 + t) * DI + d] = __float2bfloat16(y * sil);
  }
}

// ---------------------------------------------------------------------------
extern "C" void kernel_launch(void* const* d_in, const int* in_sizes, int n_in,
                              void* d_out, int out_size, void* d_ws, size_t ws_size,
                              hipStream_t stream)
{
  const float* x     = (const float*)d_in[0];
  const float* W_in  = (const float*)d_in[1];
  const float* W_x   = (const float*)d_in[2];
  const float* W_dt  = (const float*)d_in[3];
  const float* b_dt  = (const float*)d_in[4];
  const float* Dv    = (const float*)d_in[6];
  const float* W_out = (const float*)d_in[7];
  float* out = (float*)d_out;

  char* w = (char*)d_ws;
  float* BCp     = (float*)w;    w += (size_t)KS * TOK * 32 * 4;
  float* Wcp     = (float*)w;    w += (size_t)4 * DI * DM * 4;
  float* Op      = (float*)w;    w += (size_t)KSO * TOK * DM * 4;   // 50 MB
  float* sdt     = (float*)w;    w += (size_t)BATCH * NC * DI * 4;
  ushort_t* S    = (ushort_t*)w; w += (size_t)BATCH * NC * NST * DI * 2;
  ushort_t* Cr   = (ushort_t*)w; w += (size_t)BATCH * NC * NST * DI * 2;
  ushort_t* dtb  = (ushort_t*)w; w += (size_t)TOK * DI * 2;
  bf16* x_bf     = (bf16*)w;     w += (size_t)TOK * DM * 2;
  bf16* xz_bf    = (bf16*)w;     w += (size_t)TOK * 2 * DI * 2;
  bf16* yg_bf    = (bf16*)w;     w += (size_t)TOK * DI * 2;
  bf16* Bt_big   = (bf16*)w;     w += (size_t)NBIG * DM * 2;   // [4608][768]
  bf16* Wt_dt    = (bf16*)w;     w += (size_t)DI * DI * 2;
  bf16* Wt_out   = (bf16*)w;     w += (size_t)DM * DI * 2;
  bf16* Win_bf   = (bf16*)w;     w += (size_t)DM * 2 * DI * 2;

  // 1) merged prep: weight transposes + casts
  const int ncast = (TOK * DM + DM * 2 * DI) / 1024;   // 5376 blocks
  prep_all<<<5760 + ncast, 256, 0, stream>>>(x, W_in, W_dt, W_out,
                                             x_bf, Win_bf, Bt_big, Wt_dt, Wt_out);
  // 2-3) Wcomb^T = (W_in[:,:DI] @ W_dt)^T, split-K x4 -> bf16
  bgemm64p<<<dim3(DM / 128, DI / 64, 4), 256, 0, stream>>>(
      Wt_dt, DI, Win_bf, 2 * DI, Wcp, DM, (size_t)DI * DM, DI / 4);
  wcomb_reduce<<<(DI * DM) / 1024, 256, 0, stream>>>(Wcp, Bt_big + (size_t)(2 * DI) * DM);
  // 4) mega: [xz | dt] = x @ [W_in | Wcomb]   [4096x768]@[768x4608]
  //    256x288 tiles, 8 waves, grid 16x16 = 256 blocks (zero tail)
  bgemm_mega8<<<256, 512, 0, stream>>>(
      x_bf, Bt_big, b_dt, xz_bf, (bf16*)dtb);
  // 5) BC partials (summed in scan staging)
  bc_partial<<<dim3(TOK / 8, KS), 256, 0, stream>>>((const ushort_t*)xz_bf, W_x, BCp);
  // 6-8) chunked parallel scan
  scan_phase1<<<dim3(DI / 256, NC, BATCH), 256, 0, stream>>>(
      (const ushort_t*)xz_bf, dtb, BCp, S, sdt);
  scan_phase2<<<(BATCH * NST * DI) / 256, 256, 0, stream>>>(S, sdt, Cr);
  scan_phase3<<<dim3(DI / 256, NC, BATCH), 256, 0, stream>>>(
      (const ushort_t*)xz_bf, dtb, BCp, Dv, Cr, yg_bf);
  // 9-10) out = yg @ W_out, 128-tile split-K x4 partials + reduce
  bgemm_sk<<<dim3(DM / 128, TOK / 128, KSO), 256, 0, stream>>>(
      yg_bf, DI, Wt_out, DI, Op, DM, DI / KSO);
  out_reduce<<<(TOK * DM) / 1024, 256, 0, stream>>>(Op, out);
}

// Round 7
// 285.880 us; speedup vs baseline: 1.1625x; 1.1625x over previous
//
#include <hip/hip_runtime.h>
#include <hip/hip_bf16.h>
#include <cmath>

#define DM    768
#define DI    1536
#define NST   16
#define BATCH 2
#define SEQ   2048
#define TOK   (BATCH*SEQ)   // 4096
#define NC    64            // chunks per sequence
#define CL    32            // chunk length (NC*CL == SEQ)
#define KS    4             // split-K factor for BC projection
#define NBIG  (2*DI + DI)   // 4608 mega-GEMM output columns
#define KSO   4             // split-K factor for out-GEMM

#define BKK   64
#define NKT   (DM / BKK)    // 12 K-tiles for mega GEMM

typedef __hip_bfloat16 bf16;
typedef __attribute__((ext_vector_type(8))) short   short8;
typedef __attribute__((ext_vector_type(4))) float   floatx4;

typedef unsigned short ushort_t;
typedef unsigned int   uint_t;

__device__ __forceinline__ float b2f(ushort_t u)
{ return __uint_as_float(((uint_t)u) << 16); }
__device__ __forceinline__ ushort_t f2b(float f)
{ bf16 h = __float2bfloat16(f); return *(ushort_t*)&h; }

// ---------------------------------------------------------------------------
// async global->LDS, 16B per lane.
// ---------------------------------------------------------------------------
typedef __attribute__((address_space(1))) const void gvoid;
typedef __attribute__((address_space(3))) void lvoid;
__device__ __forceinline__ void gl_lds16(const void* g, void* lds_base)
{
  __builtin_amdgcn_global_load_lds((gvoid*)(uintptr_t)g,
                                   (lvoid*)(uint32_t)(uintptr_t)lds_base,
                                   16, 0, 0);
}

// fast softplus: max(v,0) + log(1+exp(-|v|))
__device__ __forceinline__ float softplus_f(float v)
{
  return fmaxf(v, 0.f) + __logf(1.f + __expf(-fabsf(v)));
}

// ---------------------------------------------------------------------------
// MEGA GEMM, 8-phase 256x256 tile (ROUND 7 = exact R2 revert; best measured
// 74.3us). R3/R5/R6 taught: every zero-tail tiling of N=4608 needs >=236
// unified VGPR+AGPR per wave -> spill (R6: acc144 AGPR + 128 VGPR = 272>256,
// FETCH 36.6->96.8MB). 288-block/2-round makespan is this kernel's floor.
// 8 waves (2M x 4N), BK=64, 128 KiB LDS, XOR-swizzled (st-slot ^= row&7),
// inline-asm ds_read_b128, counted vmcnt(2) at P4/P8 only.
// ---------------------------------------------------------------------------
__global__ __launch_bounds__(512, 2)
void bgemm_mega8(const bf16* __restrict__ A,
                 const bf16* __restrict__ Bt,
                 const float* __restrict__ bias,
                 bf16* __restrict__ Cxz,
                 bf16* __restrict__ Cdt)
{
  // [sA0 | sA1 | sB0 | sB1], each 256x64 shorts (16384), total 128 KiB
  __shared__ __align__(16) short smem[4 * 256 * 64];

  const int tid  = threadIdx.x;
  const int lane = tid & 63;
  const int wv   = tid >> 6;      // 0..7
  const int wm   = wv >> 2;       // 0..1  (M half)
  const int wn   = wv & 3;        // 0..3  (N quarter)

  // XCD-aware bijective swizzle (288 = 8*36), m fastest within XCD
  const int nb = (blockIdx.x & 7) * 36 + (blockIdx.x >> 3);
  const int m0 = (nb & 15) << 8;
  const int n0 = (nb >> 4) << 8;

  const int srow8 = lane >> 3;
  const int scol  = ((lane & 7) ^ srow8) << 3;   // pre-swizzled source col
  const int fr    = lane & 15;
  const int fq    = lane >> 4;
  const int xsw   = (fr & 7) << 3;               // ds_read short-offset XOR

  const int fq8x = (fq * 8) ^ (xsw & 24);
  const int k0x  = (xsw & 32);
  const uint32_t lbase = (uint32_t)(uintptr_t)smem;
  const uint32_t aB0 = lbase + (uint32_t)((wm*128 + fr) * 128 + 2*(k0x + fq8x));
  const uint32_t aB1 = lbase + (uint32_t)((wm*128 + fr) * 128 + 2*((32 ^ k0x) + fq8x));
  const uint32_t bB0 = lbase + 65536u + (uint32_t)((wn*64 + fr) * 128 + 2*(k0x + fq8x));
  const uint32_t bB1 = lbase + 65536u + (uint32_t)((wn*64 + fr) * 128 + 2*((32 ^ k0x) + fq8x));

  floatx4 acc[8][4];
  #pragma unroll
  for (int i = 0; i < 8; ++i)
    #pragma unroll
    for (int j = 0; j < 4; ++j)
      acc[i][j] = (floatx4){0.f, 0.f, 0.f, 0.f};

  short8 Af[8], Bf[8];

  #define STG_A(buf, c, kt)                                                   \
    gl_lds16(A + (size_t)(m0 + (c)*64 + wv*8 + srow8) * DM + (kt) + scol,     \
             smem + (buf)*16384 + (c)*4096 + wv*512)
  #define STG_B(buf, c, kt)                                                   \
    gl_lds16(Bt + (size_t)(n0 + (c)*64 + wv*8 + srow8) * DM + (kt) + scol,    \
             smem + 32768 + (buf)*16384 + (c)*4096 + wv*512)

  #define DSR(dst, a) asm volatile("ds_read_b128 %0, %1" : "=v"(dst) : "v"(a))

  #define LDA8(bo, mo) {                                                      \
    DSR(Af[0], aB0 + (bo) + (mo));          DSR(Af[1], aB1 + (bo) + (mo));    \
    DSR(Af[2], aB0 + (bo) + (mo) + 2048);   DSR(Af[3], aB1 + (bo) + (mo) + 2048); \
    DSR(Af[4], aB0 + (bo) + (mo) + 4096);   DSR(Af[5], aB1 + (bo) + (mo) + 4096); \
    DSR(Af[6], aB0 + (bo) + (mo) + 6144);   DSR(Af[7], aB1 + (bo) + (mo) + 6144); }
  #define LDB4_0(bo, no) {                                                    \
    DSR(Bf[0], bB0 + (bo) + (no));          DSR(Bf[1], bB1 + (bo) + (no));    \
    DSR(Bf[2], bB0 + (bo) + (no) + 2048);   DSR(Bf[3], bB1 + (bo) + (no) + 2048); }
  #define LDB4_1(bo, no) {                                                    \
    DSR(Bf[4], bB0 + (bo) + (no));          DSR(Bf[5], bB1 + (bo) + (no));    \
    DSR(Bf[6], bB0 + (bo) + (no) + 2048);   DSR(Bf[7], bB1 + (bo) + (no) + 2048); }

  #define MM16(mh, nh)                                                        \
    { __builtin_amdgcn_sched_barrier(0);                                      \
      __builtin_amdgcn_s_setprio(1);                                          \
      _Pragma("unroll") for (int mf = 0; mf < 4; ++mf)                        \
      _Pragma("unroll") for (int nf = 0; nf < 2; ++nf)                        \
      _Pragma("unroll") for (int kk = 0; kk < 2; ++kk)                        \
        acc[(mh)*4+mf][(nh)*2+nf] = __builtin_amdgcn_mfma_f32_16x16x32_bf16(  \
            Af[mf*2+kk], Bf[(nh)*4+nf*2+kk], acc[(mh)*4+mf][(nh)*2+nf],0,0,0);\
      __builtin_amdgcn_s_setprio(0);                                          \
      __builtin_amdgcn_sched_barrier(0); }

  #define BAR()   __builtin_amdgcn_s_barrier()
  #define LGKM0() asm volatile("s_waitcnt lgkmcnt(0)" ::: "memory")
  #define VM2()   asm volatile("s_waitcnt vmcnt(2)" ::: "memory")
  #define VM0()   asm volatile("s_waitcnt vmcnt(0)" ::: "memory")

  // prologue: tile0 fully + tile1 A0,A2; leave tile1's 2 chunks in flight
  STG_A(0,0,0); STG_A(0,1,0); STG_A(0,2,0); STG_A(0,3,0);
  STG_B(0,0,0); STG_B(0,1,0); STG_B(0,2,0); STG_B(0,3,0);
  STG_A(1,0,BKK); STG_A(1,2,BKK);
  VM2(); BAR();

  #pragma unroll 1
  for (int it = 0; it < NKT/2; ++it) {
    const int ktb = (2*it+1) * BKK;
    const int kt2 = (2*it+2) * BKK;
    const int kt3 = (2*it+3) * BKK;
    const bool g2 = (kt2 < DM), g3 = (kt3 < DM);

    // ---- P1: quadrant (mh0,nh0) of buf0
    LDA8(0,0); LDB4_0(0,0);
    STG_A(1,1,ktb); STG_A(1,3,ktb);
    BAR(); LGKM0(); MM16(0,0); BAR();
    // ---- P2: (mh0,nh1)  [A regs reused]
    LDB4_1(0,4096);
    STG_B(1,0,ktb); STG_B(1,1,ktb);
    BAR(); LGKM0(); MM16(0,1); BAR();
    // ---- P3: (mh1,nh1)  [B nh1 regs reused]
    LDA8(0,8192);
    STG_B(1,2,ktb); STG_B(1,3,ktb);
    BAR(); LGKM0(); MM16(1,1); BAR();
    // ---- P4: (mh1,nh0)  [no ds_reads] + counted drain of tile T+1
    if (g2) { STG_A(0,0,kt2); STG_A(0,2,kt2); }
    BAR(); MM16(1,0);
    if (g2) { VM2(); } else { VM0(); }
    BAR();
    // ---- P5: (mh0,nh0) of buf1
    LDA8(32768,0); LDB4_0(32768,0);
    if (g2) { STG_A(0,1,kt2); STG_A(0,3,kt2); }
    BAR(); LGKM0(); MM16(0,0); BAR();
    // ---- P6: (mh0,nh1)
    LDB4_1(32768,4096);
    if (g2) { STG_B(0,0,kt2); STG_B(0,1,kt2); }
    BAR(); LGKM0(); MM16(0,1); BAR();
    // ---- P7: (mh1,nh1)
    LDA8(32768,8192);
    if (g2) { STG_B(0,2,kt2); STG_B(0,3,kt2); }
    BAR(); LGKM0(); MM16(1,1); BAR();
    // ---- P8: (mh1,nh0) + counted drain of tile T+2
    if (g3) { STG_A(1,0,kt3); STG_A(1,2,kt3); }
    BAR(); MM16(1,0);
    if (g3) { VM2(); } else { VM0(); }
    BAR();
  }

  #undef STG_A
  #undef STG_B
  #undef DSR
  #undef LDA8
  #undef LDB4_0
  #undef LDB4_1
  #undef MM16

  // epilogue: per-wave private staging, barrier-free
  VM0(); BAR();

  short* st = smem + wv * 1160;          // 16x72 shorts + pad per wave
  const bool isdt = (n0 >= 2 * DI);
  bf16* Cb      = isdt ? Cdt : Cxz;
  const int ldc = isdt ? DI : (2 * DI);
  const int nc0 = (isdt ? n0 - 2 * DI : n0) + wn * 64;
  float bv[4];
  #pragma unroll
  for (int nf = 0; nf < 4; ++nf)
    bv[nf] = isdt ? bias[nc0 + nf * 16 + fr] : 0.f;

  const int rr = lane >> 2;
  const int rc = (lane & 3) * 16;
  #pragma unroll
  for (int mf8 = 0; mf8 < 8; ++mf8) {
    #pragma unroll
    for (int nf = 0; nf < 4; ++nf)
      #pragma unroll
      for (int r = 0; r < 4; ++r) {
        float v = acc[mf8][nf][r];
        if (isdt) v = softplus_f(v + bv[nf]);
        st[(fq * 4 + r) * 72 + nf * 16 + fr] = (short)f2b(v);
      }
    short8 v0 = *(const short8*)&st[rr * 72 + rc];
    short8 v1 = *(const short8*)&st[rr * 72 + rc + 8];
    bf16* crow = Cb + (size_t)(m0 + wm * 128 + mf8 * 16 + rr) * ldc + nc0 + rc;
    *(short8*)(crow)     = v0;
    *(short8*)(crow + 8) = v1;
  }

  #undef BAR
  #undef LGKM0
  #undef VM2
  #undef VM0
}

// ---------------------------------------------------------------------------
// OUT GEMM: 128x128 tile, split-K x KSO, PARTIAL STORES (deterministic).
// ROUND 7: partials stored as BF16 (halves Op write+read traffic ~75MB->37MB;
// partial values O(0.5), bf16 abs err ~0.002 vs 0.25 tolerance).
// ---------------------------------------------------------------------------
__global__ __launch_bounds__(256)
void bgemm_sk(const bf16* __restrict__ A, int lda,
              const bf16* __restrict__ Bt, int ldb,
              bf16* __restrict__ Op, int ldc,
              int kLen)
{
  __shared__ short sA[2][128 * 32];
  __shared__ short sB[2][128 * 32];

  const int tid  = threadIdx.x;
  const int lane = tid & 63;
  const int wv   = tid >> 6;
  const int wm   = wv >> 1;
  const int wn   = wv & 1;
  const int m0   = blockIdx.y * 128;
  const int n0   = blockIdx.x * 128;
  const int kS   = blockIdx.z * kLen;

  const int srow = lane >> 2;
  const int skof = (lane & 3) * 8;
  const int fr   = lane & 15;
  const int fq   = lane >> 4;

  floatx4 acc[4][4];
  #pragma unroll
  for (int i = 0; i < 4; ++i)
    #pragma unroll
    for (int j = 0; j < 4; ++j)
      acc[i][j] = (floatx4){0.f, 0.f, 0.f, 0.f};

  #define STAGE_SK(p, k0)                                                     \
    { _Pragma("unroll")                                                       \
      for (int q = 0; q < 2; ++q) {                                           \
        const int r = (wv * 2 + q) * 16 + srow;                               \
        gl_lds16(A  + (size_t)(m0 + r) * lda + kS + (k0) + skof,              \
                 &sA[p][(wv * 2 + q) * 512]);                                 \
        gl_lds16(Bt + (size_t)(n0 + r) * ldb + kS + (k0) + skof,              \
                 &sB[p][(wv * 2 + q) * 512]);                                 \
      } }

  STAGE_SK(0, 0);
  int p = 0;
  for (int k0 = 0; k0 < kLen; k0 += 32, p ^= 1) {
    __syncthreads();
    if (k0 + 32 < kLen) STAGE_SK(p ^ 1, k0 + 32);

    short8 af[4], bfv[4];
    #pragma unroll
    for (int t = 0; t < 4; ++t) {
      af[t]  = *(const short8*)&sA[p][(wm * 64 + t * 16 + fr) * 32 + fq * 8];
      bfv[t] = *(const short8*)&sB[p][(wn * 64 + t * 16 + fr) * 32 + fq * 8];
    }
    #pragma unroll
    for (int i = 0; i < 4; ++i)
      #pragma unroll
      for (int j = 0; j < 4; ++j)
        acc[i][j] = __builtin_amdgcn_mfma_f32_16x16x32_bf16(af[i], bfv[j], acc[i][j], 0, 0, 0);
  }
  #undef STAGE_SK

  // bf16 partial store via per-wave LDS transpose (16B/row segments).
  __syncthreads();                       // all waves done reading sA/sB
  short* st = sA[wv >> 1] + (wv & 1) * 1160;   // 16x72 + pad per wave
  bf16* Co = Op + (size_t)blockIdx.z * ((size_t)TOK * DM);
  const int rr = lane >> 2;
  const int rc = (lane & 3) * 16;
  #pragma unroll
  for (int i = 0; i < 4; ++i) {
    #pragma unroll
    for (int j = 0; j < 4; ++j)
      #pragma unroll
      for (int r = 0; r < 4; ++r)
        st[(fq * 4 + r) * 72 + j * 16 + fr] = (short)f2b(acc[i][j][r]);
    short8 v0 = *(const short8*)&st[rr * 72 + rc];
    short8 v1 = *(const short8*)&st[rr * 72 + rc + 8];
    bf16* crow = Co + (size_t)(m0 + wm * 64 + i * 16 + rr) * ldc
                 + n0 + wn * 64 + rc;
    *(short8*)(crow)     = v0;
    *(short8*)(crow + 8) = v1;
  }
}

// sum KSO bf16 partials -> fp32 out
__global__ __launch_bounds__(256)
void out_reduce(const ushort_t* __restrict__ Op, float* __restrict__ out)
{
  const int i = (blockIdx.x * 256 + threadIdx.x) * 4;   // < TOK*DM
  float s0 = 0.f, s1 = 0.f, s2 = 0.f, s3 = 0.f;
  #pragma unroll
  for (int z = 0; z < KSO; ++z) {
    ushort4 v = *(const ushort4*)(Op + (size_t)z * TOK * DM + i);
    s0 += b2f(v.x); s1 += b2f(v.y); s2 += b2f(v.z); s3 += b2f(v.w);
  }
  *(float4*)(out + i) = (float4){s0, s1, s2, s3};
}

// ---------------------------------------------------------------------------
// bf16 MFMA GEMM, 64(M)x128(N) tile, BK=32, double-buffered, split-K part
// store (Wcomb precompute). ROUND 7: bf16 partials (values sigma~0.02,
// bf16 abs err ~1e-4 — negligible).
// ---------------------------------------------------------------------------
__global__ __launch_bounds__(256)
void bgemm64p(const bf16* __restrict__ A, int lda,
              const bf16* __restrict__ Bt, int ldb,
              bf16* __restrict__ C, int ldc,
              size_t partStride, int kLen)
{
  __shared__ short sA[2][64 * 32];
  __shared__ short sB[2][128 * 32];

  const int tid  = threadIdx.x;
  const int lane = tid & 63;
  const int wv   = tid >> 6;
  const int m0   = blockIdx.y * 64;
  const int n0   = blockIdx.x * 128;
  const int kS   = blockIdx.z * kLen;

  const int srow = lane >> 2;
  const int skof = (lane & 3) * 8;
  const int fr   = lane & 15;
  const int fq   = lane >> 4;

  floatx4 acc[4][2];
  #pragma unroll
  for (int i = 0; i < 4; ++i)
    #pragma unroll
    for (int j = 0; j < 2; ++j)
      acc[i][j] = (floatx4){0.f, 0.f, 0.f, 0.f};

  #define STAGE64(p, k0)                                                      \
    { const int ra = wv * 16 + srow;                                          \
      gl_lds16(A + (size_t)(m0 + ra) * lda + kS + (k0) + skof,                \
               &sA[p][wv * 512]);                                             \
      _Pragma("unroll")                                                       \
      for (int q = 0; q < 2; ++q) {                                           \
        const int rb = (wv * 2 + q) * 16 + srow;                              \
        gl_lds16(Bt + (size_t)(n0 + rb) * ldb + kS + (k0) + skof,             \
                 &sB[p][(wv * 2 + q) * 512]);                                 \
      } }

  STAGE64(0, 0);
  int p = 0;
  for (int k0 = 0; k0 < kLen; k0 += 32, p ^= 1) {
    __syncthreads();
    if (k0 + 32 < kLen) STAGE64(p ^ 1, k0 + 32);

    short8 af[4], bfv[2];
    #pragma unroll
    for (int t = 0; t < 4; ++t)
      af[t] = *(const short8*)&sA[p][(t * 16 + fr) * 32 + fq * 8];
    #pragma unroll
    for (int j = 0; j < 2; ++j)
      bfv[j] = *(const short8*)&sB[p][(wv * 32 + j * 16 + fr) * 32 + fq * 8];
    #pragma unroll
    for (int i = 0; i < 4; ++i)
      #pragma unroll
      for (int j = 0; j < 2; ++j)
        acc[i][j] = __builtin_amdgcn_mfma_f32_16x16x32_bf16(af[i], bfv[j], acc[i][j], 0, 0, 0);
  }
  #undef STAGE64

  bf16* Co = C + (size_t)blockIdx.z * partStride;
  const int crow0 = m0 + fq * 4;
  const int ccol0 = n0 + wv * 32 + fr;
  #pragma unroll
  for (int j = 0; j < 2; ++j) {
    const int col = ccol0 + j * 16;
    #pragma unroll
    for (int i = 0; i < 4; ++i)
      #pragma unroll
      for (int r = 0; r < 4; ++r)
        Co[(size_t)(crow0 + i * 16 + r) * ldc + col] = __float2bfloat16(acc[i][j][r]);
  }
}

// ---------------------------------------------------------------------------
// merged prep: 3 weight transposes + cast x + cast W_in (one launch).
// ---------------------------------------------------------------------------
__device__ __forceinline__ void tcast_tile(const float* W, bf16* Wt,
                                           int K, int N, int tx, int ty,
                                           int tid)
{
  __shared__ float t[32][33];
  const int n0 = tx * 32, k0 = ty * 32;
  const int x = tid & 31, y = tid >> 5;
  #pragma unroll
  for (int i = 0; i < 32; i += 8)
    t[y + i][x] = W[(size_t)(k0 + y + i) * N + n0 + x];
  __syncthreads();
  #pragma unroll
  for (int i = 0; i < 32; i += 8)
    Wt[(size_t)(n0 + y + i) * K + k0 + x] = __float2bfloat16(t[x][y + i]);
}

__global__ __launch_bounds__(256)
void prep_all(const float* __restrict__ x,    const float* __restrict__ W_in,
              const float* __restrict__ W_dt, const float* __restrict__ W_out,
              bf16* __restrict__ x_bf,   bf16* __restrict__ Win_bf,
              bf16* __restrict__ Bt_big, bf16* __restrict__ Wt_dt,
              bf16* __restrict__ Wt_out)
{
  const int bid = blockIdx.x;
  const int tid = threadIdx.x;
  if (bid < 2304) {
    tcast_tile(W_in,  Bt_big, DM, 2 * DI, bid % 96, bid / 96, tid);
  } else if (bid < 4608) {
    int b = bid - 2304;
    tcast_tile(W_dt,  Wt_dt,  DI, DI,     b % 48,  b / 48,  tid);
  } else if (bid < 5760) {
    int b = bid - 4608;
    tcast_tile(W_out, Wt_out, DI, DM,     b % 24,  b / 24,  tid);
  } else {
    const int n1 = TOK * DM;                  // x elements
    int i = (bid - 5760) * 1024 + tid * 4;
    const float* s; bf16* d;
    if (i < n1) { s = x; d = x_bf; }
    else        { s = W_in; d = Win_bf; i -= n1; }
    float4 v = *(const float4*)(s + i);
    d[i + 0] = __float2bfloat16(v.x); d[i + 1] = __float2bfloat16(v.y);
    d[i + 2] = __float2bfloat16(v.z); d[i + 3] = __float2bfloat16(v.w);
  }
}

// sum 4 bf16 partials -> bf16 (Wcomb reduce into Bt_big rows [3072,4608))
__global__ __launch_bounds__(256)
void wcomb_reduce(const ushort_t* __restrict__ P, bf16* __restrict__ dst)
{
  const int i = (blockIdx.x * 256 + threadIdx.x) * 4;   // < DI*DM
  float s0 = 0.f, s1 = 0.f, s2 = 0.f, s3 = 0.f;
  #pragma unroll
  for (int ks = 0; ks < 4; ++ks) {
    ushort4 v = *(const ushort4*)(P + (size_t)ks * DI * DM + i);
    s0 += b2f(v.x); s1 += b2f(v.y); s2 += b2f(v.z); s3 += b2f(v.w);
  }
  dst[i + 0] = __float2bfloat16(s0);
  dst[i + 1] = __float2bfloat16(s1);
  dst[i + 2] = __float2bfloat16(s2);
  dst[i + 3] = __float2bfloat16(s3);
}

// ---------------------------------------------------------------------------
// BC projection, split-K fp32 accumulate over bf16 x_p.
// ---------------------------------------------------------------------------
__global__ __launch_bounds__(256)
void bc_partial(const ushort_t* __restrict__ xzb, const float* __restrict__ Wx,
                float* __restrict__ BCp)
{
  const int tok = blockIdx.x * 8 + (threadIdx.x >> 5);
  const int j   = threadIdx.x & 31;
  const int k0  = blockIdx.y * (DI / KS);
  const ushort_t* xrow = xzb + (size_t)tok * (2 * DI) + k0;
  const float* wp = Wx + (size_t)k0 * 32 + j;
  float a0 = 0.f, a1 = 0.f, a2 = 0.f, a3 = 0.f;
  #pragma unroll 8
  for (int k = 0; k < DI / KS; k += 4) {
    ushort4 xv = *(const ushort4*)(xrow + k);
    a0 = fmaf(b2f(xv.x), wp[(k + 0) * 32], a0);
    a1 = fmaf(b2f(xv.y), wp[(k + 1) * 32], a1);
    a2 = fmaf(b2f(xv.z), wp[(k + 2) * 32], a2);
    a3 = fmaf(b2f(xv.w), wp[(k + 3) * 32], a3);
  }
  BCp[((size_t)blockIdx.y * TOK + tok) * 32 + j] = (a0 + a1) + (a2 + a3);
}

// stage BC for a chunk: sum the KS split-K partials during LDS fill
__device__ __forceinline__ void stage_bc(const float* __restrict__ BCp,
                                         int g0, int tid, float bcs[CL][32])
{
  int t = tid >> 3, q = (tid & 7) << 2;
  float4 s = *(const float4*)(BCp + ((size_t)(g0 + t)) * 32 + q);
  #pragma unroll
  for (int ks = 1; ks < KS; ++ks) {
    float4 v = *(const float4*)(BCp + ((size_t)ks * TOK + g0 + t) * 32 + q);
    s.x += v.x; s.y += v.y; s.z += v.z; s.w += v.w;
  }
  *(float4*)&bcs[t][q] = s;
}

// ---------------------------------------------------------------------------
// Scan (3 kernels). A_n = -(n+1); dA_n = e1^(n+1), e1 = exp(-dt).
// ---------------------------------------------------------------------------
__global__ __launch_bounds__(256)
void scan_phase1(const ushort_t* __restrict__ xzb, const ushort_t* __restrict__ dtb,
                 const float* __restrict__ BCp,
                 ushort_t* __restrict__ S, float* __restrict__ sdt)
{
  const int d  = blockIdx.x * 256 + threadIdx.x;
  const int c  = blockIdx.y;
  const int b  = blockIdx.z;
  const int g0 = b * SEQ + c * CL;
  const int tid = threadIdx.x;

  __shared__ float bcs[CL][32];
  stage_bc(BCp, g0, tid, bcs);
  __syncthreads();

  float h[NST];
  #pragma unroll
  for (int n = 0; n < NST; ++n) h[n] = 0.f;
  float sd = 0.f;

  for (int t = 0; t < CL; ++t) {
    float dtv = b2f(dtb[(size_t)(g0 + t) * DI + d]);
    float xpv = b2f(xzb[(size_t)(g0 + t) * (2 * DI) + d]);
    sd += dtv;
    float xb = xpv * dtv;
    float e1 = __expf(-dtv);
    float dA = 1.f;
    #pragma unroll
    for (int n = 0; n < NST; ++n) {
      dA *= e1;
      h[n] = fmaf(dA, h[n], xb * bcs[t][n]);
    }
  }
  const size_t base = ((size_t)(b * NC + c) * NST) * DI + d;
  #pragma unroll
  for (int n = 0; n < NST; ++n) S[base + (size_t)n * DI] = f2b(h[n]);
  sdt[(size_t)(b * NC + c) * DI + d] = sd;
}

__global__ __launch_bounds__(256)
void scan_phase2(const ushort_t* __restrict__ S, const float* __restrict__ sdt,
                 ushort_t* __restrict__ Carry)
{
  const int f = blockIdx.x * 256 + threadIdx.x;   // < BATCH*NST*DI
  const int b = f / (NST * DI);
  const int r = f - b * (NST * DI);
  const int n = r / DI;
  const int d = r - n * DI;
  const float an = -(float)(n + 1);
  float carry = 0.f;
  #pragma unroll 8
  for (int c = 0; c < NC; ++c) {
    size_t idx = ((size_t)(b * NC + c) * NST + n) * DI + d;
    Carry[idx] = f2b(carry);
    float P = __expf(an * sdt[(size_t)(b * NC + c) * DI + d]);
    carry = fmaf(P, carry, b2f(S[idx]));
  }
}

__global__ __launch_bounds__(256)
void scan_phase3(const ushort_t* __restrict__ xzb, const ushort_t* __restrict__ dtb,
                 const float* __restrict__ BCp, const float* __restrict__ Dv,
                 const ushort_t* __restrict__ Carry, bf16* __restrict__ ygb)
{
  const int d  = blockIdx.x * 256 + threadIdx.x;
  const int c  = blockIdx.y;
  const int b  = blockIdx.z;
  const int g0 = b * SEQ + c * CL;
  const int tid = threadIdx.x;

  __shared__ float bcs[CL][32];
  stage_bc(BCp, g0, tid, bcs);
  __syncthreads();

  const size_t base = ((size_t)(b * NC + c) * NST) * DI + d;
  float h[NST];
  #pragma unroll
  for (int n = 0; n < NST; ++n) h[n] = b2f(Carry[base + (size_t)n * DI]);
  const float Dd = Dv[d];

  for (int t = 0; t < CL; ++t) {
    float dtv = b2f(dtb[(size_t)(g0 + t) * DI + d]);
    float xpv = b2f(xzb[(size_t)(g0 + t) * (2 * DI) + d]);
    float zv  = b2f(xzb[(size_t)(g0 + t) * (2 * DI) + DI + d]);
    float xb = xpv * dtv;
    float e1 = __expf(-dtv);
    float dA = 1.f;
    float y = 0.f;
    #pragma unroll
    for (int n = 0; n < NST; ++n) {
      dA *= e1;
      h[n] = fmaf(dA, h[n], xb * bcs[t][n]);
      y = fmaf(h[n], bcs[t][16 + n], y);
    }
    y = fmaf(xpv, Dd, y);
    float sil = zv / (1.f + __expf(-zv));
    ygb[(size_t)(g0 + t) * DI + d] = __float2bfloat16(y * sil);
  }
}

// ---------------------------------------------------------------------------
extern "C" void kernel_launch(void* const* d_in, const int* in_sizes, int n_in,
                              void* d_out, int out_size, void* d_ws, size_t ws_size,
                              hipStream_t stream)
{
  const float* x     = (const float*)d_in[0];
  const float* W_in  = (const float*)d_in[1];
  const float* W_x   = (const float*)d_in[2];
  const float* W_dt  = (const float*)d_in[3];
  const float* b_dt  = (const float*)d_in[4];
  const float* Dv    = (const float*)d_in[6];
  const float* W_out = (const float*)d_in[7];
  float* out = (float*)d_out;

  char* w = (char*)d_ws;
  float* BCp     = (float*)w;    w += (size_t)KS * TOK * 32 * 4;
  bf16* Wcp      = (bf16*)w;     w += (size_t)4 * DI * DM * 2;        // bf16
  bf16* Op       = (bf16*)w;     w += (size_t)KSO * TOK * DM * 2;     // bf16
  float* sdt     = (float*)w;    w += (size_t)BATCH * NC * DI * 4;
  ushort_t* S    = (ushort_t*)w; w += (size_t)BATCH * NC * NST * DI * 2;
  ushort_t* Cr   = (ushort_t*)w; w += (size_t)BATCH * NC * NST * DI * 2;
  ushort_t* dtb  = (ushort_t*)w; w += (size_t)TOK * DI * 2;
  bf16* x_bf     = (bf16*)w;     w += (size_t)TOK * DM * 2;
  bf16* xz_bf    = (bf16*)w;     w += (size_t)TOK * 2 * DI * 2;
  bf16* yg_bf    = (bf16*)w;     w += (size_t)TOK * DI * 2;
  bf16* Bt_big   = (bf16*)w;     w += (size_t)NBIG * DM * 2;   // [4608][768]
  bf16* Wt_dt    = (bf16*)w;     w += (size_t)DI * DI * 2;
  bf16* Wt_out   = (bf16*)w;     w += (size_t)DM * DI * 2;
  bf16* Win_bf   = (bf16*)w;     w += (size_t)DM * 2 * DI * 2;

  // 1) merged prep: weight transposes + casts
  const int ncast = (TOK * DM + DM * 2 * DI) / 1024;   // 5376 blocks
  prep_all<<<5760 + ncast, 256, 0, stream>>>(x, W_in, W_dt, W_out,
                                             x_bf, Win_bf, Bt_big, Wt_dt, Wt_out);
  // 2-3) Wcomb^T = (W_in[:,:DI] @ W_dt)^T, split-K x4 (bf16 partials) -> bf16
  bgemm64p<<<dim3(DM / 128, DI / 64, 4), 256, 0, stream>>>(
      Wt_dt, DI, Win_bf, 2 * DI, Wcp, DM, (size_t)DI * DM, DI / 4);
  wcomb_reduce<<<(DI * DM) / 1024, 256, 0, stream>>>(
      (const ushort_t*)Wcp, Bt_big + (size_t)(2 * DI) * DM);
  // 4) mega: [xz | dt] = x @ [W_in | Wcomb]   [4096x768]@[768x4608]
  bgemm_mega8<<<(NBIG / 256) * (TOK / 256), 512, 0, stream>>>(
      x_bf, Bt_big, b_dt, xz_bf, (bf16*)dtb);
  // 5) BC partials (summed in scan staging)
  bc_partial<<<dim3(TOK / 8, KS), 256, 0, stream>>>((const ushort_t*)xz_bf, W_x, BCp);
  // 6-8) chunked parallel scan
  scan_phase1<<<dim3(DI / 256, NC, BATCH), 256, 0, stream>>>(
      (const ushort_t*)xz_bf, dtb, BCp, S, sdt);
  scan_phase2<<<(BATCH * NST * DI) / 256, 256, 0, stream>>>(S, sdt, Cr);
  scan_phase3<<<dim3(DI / 256, NC, BATCH), 256, 0, stream>>>(
      (const ushort_t*)xz_bf, dtb, BCp, Dv, Cr, yg_bf);
  // 9-10) out = yg @ W_out, 128-tile split-K x4 bf16 partials + reduce
  bgemm_sk<<<dim3(DM / 128, TOK / 128, KSO), 256, 0, stream>>>(
      yg_bf, DI, Wt_out, DI, Op, DM, DI / KSO);
  out_reduce<<<(TOK * DM) / 1024, 256, 0, stream>>>((const ushort_t*)Op, out);
}